// Round 3
// baseline (172.548 us; speedup 1.0000x reference)
//
#include <hip/hip_runtime.h>
#include <math.h>

#define BATCH   256
#define NQ      1000
#define NC      80
#define NDET    300
#define THREADS 1024
#define SCORE_TH 0.05f

// DIAGNOSTIC BUILD: phase A (global loads + argmax reduce) repeated 6x with
// an opaque address offset so the dispatch exceeds the ~50us poison fills and
// surfaces in the rocprof top-5 with full counters. Output is bit-identical
// to the round-2 kernel (each rep recomputes/rewrites the same keys).
#define DIAG_REPS 6

typedef unsigned long long u64;

// key = (sigmoid_bits << 32) | ((1023 - q) << 10) | label
//   u64-descending == (score desc, q asc) == jax.lax.top_k's stable order.

// argmax over one query's 80 logits, spread across a 4-lane group.
// After the 2-round butterfly ALL 4 lanes hold the group winner.
__device__ __forceinline__ void argmax20(const float4* v, int r,
                                         float& bv_out, int& bc_out)
{
    float bv = -1e30f; int bc = 0;
    #pragma unroll
    for (int i = 0; i < 5; ++i) {
        float4 x = v[i]; int c = 16 * i + 4 * r;
        if (x.x > bv) { bv = x.x; bc = c + 0; }   // strict >: lowest class wins
        if (x.y > bv) { bv = x.y; bc = c + 1; }
        if (x.z > bv) { bv = x.z; bc = c + 2; }
        if (x.w > bv) { bv = x.w; bc = c + 3; }
    }
    #pragma unroll
    for (int d = 1; d <= 2; d <<= 1) {
        float ov = __shfl_xor(bv, d);
        int   oc = __shfl_xor(bc, d);
        if (ov > bv || (ov == bv && oc < bc)) { bv = ov; bc = oc; }
    }
    bv_out = bv; bc_out = bc;
}

__global__ __launch_bounds__(THREADS) void rtdetr_fused_diag(
    const float* __restrict__ logits,   // [B, Q, C]
    const float* __restrict__ boxes,    // [B, Q, 4]
    const float* __restrict__ sizes,    // [B, 2] (h, w)
    float* __restrict__ out)            // scores | labels | boxes
{
    __shared__ u64    s_k[THREADS];     // 8 KB
    __shared__ float4 s_box[NQ];        // 16 KB

    const int b = blockIdx.x;
    const int t = threadIdx.x;
    const int r = t & 3;                // sub-slice within 4-lane group
    const int g = t >> 2;               // group id 0..255

    // Stage boxes row into a register (no consumer -> no vmcnt stall here).
    float4 boxreg = make_float4(0.0f, 0.0f, 0.0f, 0.0f);
    if (t < NQ) boxreg = ((const float4*)boxes)[b * NQ + t];

    const float4* gbase = (const float4*)(logits + (size_t)b * NQ * NC);
    const int mq = (r << 8) + g;        // this thread's emitted query id

    // ---- phase A, repeated DIAG_REPS times (diagnostic) ----
    #pragma unroll 1
    for (int rep = 0; rep < DIAG_REPS; ++rep) {
        int zoff = 0;
        asm volatile("" : "+v"(zoff));  // opaque 0: defeats load CSE across reps

        float q0v, q1v, q2v, q3v; int q0c, q1c, q2c, q3c;
        {
            const float4* A = gbase + (size_t)(g + zoff      ) * 20;
            const float4* B = gbase + (size_t)(g + zoff + 256) * 20;
            float4 va[5], vb[5];
            #pragma unroll
            for (int i = 0; i < 5; ++i) va[i] = A[4 * i + r];
            #pragma unroll
            for (int i = 0; i < 5; ++i) vb[i] = B[4 * i + r];
            argmax20(va, r, q0v, q0c);
            argmax20(vb, r, q1v, q1c);
        }
        {
            const int qlast = min(g + zoff + 768, NQ - 1);   // clamp address
            const float4* A = gbase + (size_t)(g + zoff + 512) * 20;
            const float4* B = gbase + (size_t)qlast * 20;
            float4 va[5], vb[5];
            #pragma unroll
            for (int i = 0; i < 5; ++i) va[i] = A[4 * i + r];
            #pragma unroll
            for (int i = 0; i < 5; ++i) vb[i] = B[4 * i + r];
            argmax20(va, r, q2v, q2c);
            argmax20(vb, r, q3v, q3c);
        }

        // Lane-spread key emission: lane r takes query r*256+g.
        float mv = (r == 0) ? q0v : (r == 1) ? q1v : (r == 2) ? q2v : q3v;
        int   mc = (r == 0) ? q0c : (r == 1) ? q1c : (r == 2) ? q2c : q3c;

        float sc = 1.0f / (1.0f + expf(-mv));
        unsigned int kb = (sc > SCORE_TH) ? __float_as_uint(sc) : 0u;
        u64 kk = ((u64)kb << 32) |
                 ((unsigned int)(1023 - mq) << 10) | (unsigned int)mc;
        if (mq >= NQ) kk = 0ull;                  // pad entries sort last
        s_k[mq] = kk;                             // same value every rep
    }
    if (t < NQ) s_box[t] = boxreg;                // deferred LDS stage
    __syncthreads();

    // ---- phase B: hybrid bitonic sort, descending ----
    u64 v = s_k[t];
    for (int k = 2; k <= THREADS; k <<= 1) {
        for (int j = k >> 1; j > 0; j >>= 1) {
            u64 o;
            if (j >= 64) {
                __syncthreads();          // protect previous reads of s_k
                s_k[t] = v;
                __syncthreads();
                o = s_k[t ^ j];
            } else {
                o = __shfl_xor(v, j);
            }
            const bool takeMax = (((t & j) == 0) == ((t & k) == 0));
            if (takeMax ? (o > v) : (o < v)) v = o;
        }
    }

    // ---- emit: thread t holds the exact stable rank-t entry ----
    if (t < NDET) {
        unsigned int key = (unsigned int)(v >> 32);

        float* out_scores = out;
        float* out_labels = out + (size_t)BATCH * NDET;
        float* out_boxes  = out + (size_t)2 * BATCH * NDET;
        const int o = b * NDET + t;

        if (key != 0u) {
            int lab = (int)(v & 0x3FFull);
            int idx = 1023 - (int)((v >> 10) & 0x3FFull);
            out_scores[o] = __uint_as_float(key);
            out_labels[o] = (float)lab;
            float4 bx = s_box[idx];                  // cx, cy, w, h (LDS gather)
            const float img_h = sizes[2 * b + 0];
            const float img_w = sizes[2 * b + 1];
            float4 ob;
            ob.x = (bx.x - 0.5f * bx.z) * img_w;
            ob.y = (bx.y - 0.5f * bx.w) * img_h;
            ob.z = (bx.x + 0.5f * bx.z) * img_w;
            ob.w = (bx.y + 0.5f * bx.w) * img_h;
            ((float4*)out_boxes)[o] = ob;
        } else {
            out_scores[o] = 0.0f;
            out_labels[o] = -1.0f;
            ((float4*)out_boxes)[o] = make_float4(0.0f, 0.0f, 0.0f, 0.0f);
        }
    }
}

extern "C" void kernel_launch(void* const* d_in, const int* in_sizes, int n_in,
                              void* d_out, int out_size, void* d_ws, size_t ws_size,
                              hipStream_t stream) {
    const float* logits = (const float*)d_in[0];   // [256,1000,80]
    const float* boxes  = (const float*)d_in[1];   // [256,1000,4]
    const float* sizes  = (const float*)d_in[2];   // [256,2]
    float* out = (float*)d_out;                    // 460800 floats

    rtdetr_fused_diag<<<BATCH, THREADS, 0, stream>>>(logits, boxes, sizes, out);
}

// Round 4
// 131.485 us; speedup vs baseline: 1.3123x; 1.3123x over previous
//
#include <hip/hip_runtime.h>
#include <math.h>

#define BATCH   256
#define NQ      1000
#define NC      80
#define NDET    300
#define THREADS 1024
#define SCORE_TH 0.05f

typedef unsigned long long u64;

// key = (sigmoid_bits << 32) | ((1023 - q) << 10) | label
//   u64-descending == (score desc, q asc) == jax.lax.top_k's stable order;
//   the (1023-q) field is unique per q, so label bits never affect order.
//
// Phase B restructure (round 4):
//   * stages k=2..64 run per-wave on register keys BEFORE the first barrier
//     (hidden under other waves' phase-A memory waits; partners t^j, j<=32
//     stay in-wave; direction formula uses the global position t unchanged)
//   * stages k=128..1024 run on 256 threads x 4 registers (element e = 4t+s):
//     j>=256 -> LDS (3 stages, 6 barriers total, was 10/20)
//     4<=j<=128 -> shfl_xor by j/4 (partner thread t^(j/4), same slot)
//     j in {1,2} -> pure register compare-exchange (off the LDS pipe)

// argmax over one query's 80 logits, spread across a 4-lane group.
// After the 2-round butterfly ALL 4 lanes hold the group winner.
__device__ __forceinline__ void argmax20(const float4* v, int r,
                                         float& bv_out, int& bc_out)
{
    float bv = -1e30f; int bc = 0;
    #pragma unroll
    for (int i = 0; i < 5; ++i) {
        float4 x = v[i]; int c = 16 * i + 4 * r;
        if (x.x > bv) { bv = x.x; bc = c + 0; }   // strict >: lowest class wins
        if (x.y > bv) { bv = x.y; bc = c + 1; }
        if (x.z > bv) { bv = x.z; bc = c + 2; }
        if (x.w > bv) { bv = x.w; bc = c + 3; }
    }
    #pragma unroll
    for (int d = 1; d <= 2; d <<= 1) {
        float ov = __shfl_xor(bv, d);
        int   oc = __shfl_xor(bc, d);
        if (ov > bv || (ov == bv && oc < bc)) { bv = ov; bc = oc; }
    }
    bv_out = bv; bc_out = bc;
}

// per-slot output materialization (emit)
#define PROC(E, SC, LB, OB) do {                                        \
    unsigned int _key = (unsigned int)((E) >> 32);                      \
    if (_key != 0u) {                                                   \
        int _lab = (int)((E) & 0x3FFull);                               \
        int _idx = 1023 - (int)(((E) >> 10) & 0x3FFull);                \
        SC = __uint_as_float(_key); LB = (float)_lab;                   \
        float4 _bx = s_box[_idx];                                       \
        OB.x = (_bx.x - 0.5f * _bx.z) * img_w;                          \
        OB.y = (_bx.y - 0.5f * _bx.w) * img_h;                          \
        OB.z = (_bx.x + 0.5f * _bx.z) * img_w;                          \
        OB.w = (_bx.y + 0.5f * _bx.w) * img_h;                          \
    } else {                                                            \
        SC = 0.0f; LB = -1.0f;                                          \
        OB = make_float4(0.0f, 0.0f, 0.0f, 0.0f);                       \
    }                                                                   \
} while (0)

__global__ __launch_bounds__(THREADS) void rtdetr_fused(
    const float* __restrict__ logits,   // [B, Q, C]
    const float* __restrict__ boxes,    // [B, Q, 4]
    const float* __restrict__ sizes,    // [B, 2] (h, w)
    float* __restrict__ out)            // scores | labels | boxes
{
    __shared__ u64    s_k[THREADS];     // 8 KB
    __shared__ float4 s_box[NQ];        // 16 KB

    const int b = blockIdx.x;
    const int t = threadIdx.x;
    const int r = t & 3;                // sub-slice within 4-lane group
    const int g = t >> 2;               // group id 0..255

    // Stage boxes row into a register (no consumer -> no vmcnt stall here);
    // LDS write deferred until after phase A.
    float4 boxreg = make_float4(0.0f, 0.0f, 0.0f, 0.0f);
    if (t < NQ) boxreg = ((const float4*)boxes)[b * NQ + t];

    const float4* gbase = (const float4*)(logits + (size_t)b * NQ * NC);

    // ---- phase A: 2 superpasses x 2 queries; ALL loads unconditional ----
    float q0v, q1v, q2v, q3v; int q0c, q1c, q2c, q3c;
    {
        const float4* A = gbase + (size_t)(g      ) * 20;
        const float4* B = gbase + (size_t)(256 + g) * 20;
        float4 va[5], vb[5];
        #pragma unroll
        for (int i = 0; i < 5; ++i) va[i] = A[4 * i + r];
        #pragma unroll
        for (int i = 0; i < 5; ++i) vb[i] = B[4 * i + r];
        argmax20(va, r, q0v, q0c);
        argmax20(vb, r, q1v, q1c);
    }
    {
        const int qlast = min(768 + g, NQ - 1);       // clamp address
        const float4* A = gbase + (size_t)(512 + g) * 20;
        const float4* B = gbase + (size_t)qlast * 20;
        float4 va[5], vb[5];
        #pragma unroll
        for (int i = 0; i < 5; ++i) va[i] = A[4 * i + r];
        #pragma unroll
        for (int i = 0; i < 5; ++i) vb[i] = B[4 * i + r];
        argmax20(va, r, q2v, q2c);
        argmax20(vb, r, q3v, q3c);
    }

    // Lane-spread key build: lane r takes query r*256+g (bijective 0..1023).
    float mv = (r == 0) ? q0v : (r == 1) ? q1v : (r == 2) ? q2v : q3v;
    int   mc = (r == 0) ? q0c : (r == 1) ? q1c : (r == 2) ? q2c : q3c;
    const int mq = (r << 8) + g;

    float sc = 1.0f / (1.0f + expf(-mv));
    unsigned int kb = (sc > SCORE_TH) ? __float_as_uint(sc) : 0u;
    u64 v = ((u64)kb << 32) |
            ((unsigned int)(1023 - mq) << 10) | (unsigned int)mc;
    if (mq >= NQ) v = 0ull;                           // pad entries sort last

    // ---- phase B.1: intra-wave bitonic k=2..64 (pre-barrier, hidden) ----
    #pragma unroll
    for (int k = 2; k <= 64; k <<= 1) {
        #pragma unroll
        for (int j = k >> 1; j > 0; j >>= 1) {
            u64 o = __shfl_xor(v, j);
            const bool takeMax = (((t & j) == 0) == ((t & k) == 0));
            if (takeMax ? (o > v) : (o < v)) v = o;
        }
    }

    s_k[t] = v;                         // position t holds its sorted-run value
    if (t < NQ) s_box[t] = boxreg;      // deferred LDS stage
    __syncthreads();

    // ---- phase B.2: merge k=128..1024, 256 threads x 4 elements ----
    const bool m = (t < 256);
    u64 e0 = 0, e1 = 0, e2 = 0, e3 = 0;
    if (m) {
        const u64* p = &s_k[t << 2];
        e0 = p[0]; e1 = p[1]; e2 = p[2]; e3 = p[3];
    }

    #pragma unroll
    for (int k = 128; k <= 1024; k <<= 1) {
        const int kt = k >> 2;
        #pragma unroll
        for (int j = k >> 1; j >= 4; j >>= 1) {
            const int jt = j >> 2;
            if (jt >= 64) {
                // cross-wave: LDS exchange (all threads hit both barriers)
                __syncthreads();
                if (m) { u64* p = &s_k[t << 2]; p[0]=e0; p[1]=e1; p[2]=e2; p[3]=e3; }
                __syncthreads();
                if (m) {
                    const u64* p = &s_k[(t ^ jt) << 2];
                    u64 o0 = p[0], o1 = p[1], o2 = p[2], o3 = p[3];
                    const bool takeMax = (((t & jt) == 0) == ((t & kt) == 0));
                    if (takeMax ? (o0 > e0) : (o0 < e0)) e0 = o0;
                    if (takeMax ? (o1 > e1) : (o1 < e1)) e1 = o1;
                    if (takeMax ? (o2 > e2) : (o2 < e2)) e2 = o2;
                    if (takeMax ? (o3 > e3) : (o3 < e3)) e3 = o3;
                }
            } else {
                if (m) {
                    u64 o0 = __shfl_xor(e0, jt), o1 = __shfl_xor(e1, jt);
                    u64 o2 = __shfl_xor(e2, jt), o3 = __shfl_xor(e3, jt);
                    const bool takeMax = (((t & jt) == 0) == ((t & kt) == 0));
                    if (takeMax ? (o0 > e0) : (o0 < e0)) e0 = o0;
                    if (takeMax ? (o1 > e1) : (o1 < e1)) e1 = o1;
                    if (takeMax ? (o2 > e2) : (o2 < e2)) e2 = o2;
                    if (takeMax ? (o3 > e3) : (o3 < e3)) e3 = o3;
                }
            }
        }
        // j=2 and j=1: intra-thread register compare-exchange.
        // dir uniform across slots (k >= 128): dk = ((e & k) == 0).
        if (m) {
            const bool dk = ((t & kt) == 0);
            { u64 mx = e0 > e2 ? e0 : e2, mn = e0 > e2 ? e2 : e0; e0 = dk ? mx : mn; e2 = dk ? mn : mx; }
            { u64 mx = e1 > e3 ? e1 : e3, mn = e1 > e3 ? e3 : e1; e1 = dk ? mx : mn; e3 = dk ? mn : mx; }
            { u64 mx = e0 > e1 ? e0 : e1, mn = e0 > e1 ? e1 : e0; e0 = dk ? mx : mn; e1 = dk ? mn : mx; }
            { u64 mx = e2 > e3 ? e2 : e3, mn = e2 > e3 ? e3 : e2; e2 = dk ? mx : mn; e3 = dk ? mn : mx; }
        }
    }

    // ---- emit: thread t < 75 holds ranks 4t..4t+3; fully vectorized ----
    if (t < NDET / 4) {
        const float img_h = sizes[2 * b + 0];
        const float img_w = sizes[2 * b + 1];

        float4 osc, olb, ob0, ob1, ob2, ob3;
        PROC(e0, osc.x, olb.x, ob0);
        PROC(e1, osc.y, olb.y, ob1);
        PROC(e2, osc.z, olb.z, ob2);
        PROC(e3, osc.w, olb.w, ob3);

        float* out_scores = out;
        float* out_labels = out + (size_t)BATCH * NDET;
        float* out_boxes  = out + (size_t)2 * BATCH * NDET;

        ((float4*)(out_scores + (size_t)b * NDET))[t] = osc;   // b*1200B: 16B-aligned
        ((float4*)(out_labels + (size_t)b * NDET))[t] = olb;
        float4* ob = (float4*)out_boxes + (size_t)b * NDET + 4 * t;
        ob[0] = ob0; ob[1] = ob1; ob[2] = ob2; ob[3] = ob3;
    }
}

extern "C" void kernel_launch(void* const* d_in, const int* in_sizes, int n_in,
                              void* d_out, int out_size, void* d_ws, size_t ws_size,
                              hipStream_t stream) {
    const float* logits = (const float*)d_in[0];   // [256,1000,80]
    const float* boxes  = (const float*)d_in[1];   // [256,1000,4]
    const float* sizes  = (const float*)d_in[2];   // [256,2]
    float* out = (float*)d_out;                    // 460800 floats

    rtdetr_fused<<<BATCH, THREADS, 0, stream>>>(logits, boxes, sizes, out);
}